// Round 1
// baseline (133.678 us; speedup 1.0000x reference)
//
#include <hip/hip_runtime.h>
#include <math.h>

#define N_NODES 8192
#define NE      262144
#define F       128

// ---------------- K1: init deg=1 (self loop), counts=0 ----------------
__global__ void k_init(float* __restrict__ deg, int* __restrict__ counts) {
    int i = blockIdx.x * blockDim.x + threadIdx.x;
    if (i < N_NODES) { deg[i] = 1.0f; counts[i] = 0; }
}

// ---------------- K2: deg[r] += w[e]; counts[r]++ ----------------
__global__ void k_deg(const int* __restrict__ adj, const float* __restrict__ ew,
                      float* __restrict__ deg, int* __restrict__ counts) {
    int e = blockIdx.x * blockDim.x + threadIdx.x;
    if (e < NE) {
        int r = adj[e];          // adj[0][e] = source row
        atomicAdd(&deg[r], ew[e]);
        atomicAdd(&counts[r], 1);
    }
}

// ---------------- K3: dinv = 1/sqrt(deg + eps) ----------------
__global__ void k_dinv(const float* __restrict__ deg, float* __restrict__ dinv) {
    int i = blockIdx.x * blockDim.x + threadIdx.x;
    if (i < N_NODES) dinv[i] = 1.0f / sqrtf(deg[i] + 1e-10f);
}

// ---------------- K4: exclusive scan of counts -> offsets, cursor ----------------
// Single block, 1024 threads, 8 elems/thread.
__global__ __launch_bounds__(1024) void k_scan(const int* __restrict__ counts,
                                               int* __restrict__ offsets,
                                               int* __restrict__ cursor) {
    __shared__ int lds[1024];
    int t = threadIdx.x;
    int c[8];
    int s = 0;
#pragma unroll
    for (int j = 0; j < 8; j++) { c[j] = counts[t * 8 + j]; s += c[j]; }
    lds[t] = s;
    __syncthreads();
    for (int off = 1; off < 1024; off <<= 1) {
        int v = (t >= off) ? lds[t - off] : 0;
        __syncthreads();
        lds[t] += v;
        __syncthreads();
    }
    int run = lds[t] - s;  // exclusive prefix for this thread's chunk
#pragma unroll
    for (int j = 0; j < 8; j++) {
        offsets[t * 8 + j] = run;
        cursor[t * 8 + j]  = run;
        run += c[j];
    }
    if (t == 1023) offsets[N_NODES] = run;  // == NE
}

// ---------------- K5: scatter edges into CSR, fold coef = w*dinv[col] ----------------
__global__ void k_scatter(const int* __restrict__ adj, const float* __restrict__ ew,
                          const float* __restrict__ dinv, int* __restrict__ cursor,
                          int2* __restrict__ csr) {
    int e = blockIdx.x * blockDim.x + threadIdx.x;
    if (e < NE) {
        int r = adj[e];
        int c = adj[NE + e];
        float coef = ew[e] * dinv[c];
        int pos = atomicAdd(&cursor[r], 1);
        csr[pos] = make_int2(c, __float_as_int(coef));
    }
}

// ---------------- K6: support = x @ W  (M=8192, K=128, N=128, fp32 VALU) ----------
// 8 rows per block; thread (c, rb) accumulates rows rb, rb+2, rb+4, rb+6 at col c.
__global__ __launch_bounds__(256) void k_gemm(const float* __restrict__ x,
                                              const float* __restrict__ w,
                                              float* __restrict__ support) {
    __shared__ float xs[8][F];
    int t = threadIdx.x;
    int row0 = blockIdx.x * 8;
    // stage 8 rows of x (1024 floats) via one float4 per thread
    ((float4*)&xs[0][0])[t] = ((const float4*)(x + (size_t)row0 * F))[t];
    __syncthreads();
    int c  = t & (F - 1);
    int rb = t >> 7;  // 0 or 1
    float a0 = 0.f, a1 = 0.f, a2 = 0.f, a3 = 0.f;
#pragma unroll 8
    for (int k = 0; k < F; k++) {
        float wv = w[k * F + c];
        a0 += xs[rb + 0][k] * wv;
        a1 += xs[rb + 2][k] * wv;
        a2 += xs[rb + 4][k] * wv;
        a3 += xs[rb + 6][k] * wv;
    }
    support[(size_t)(row0 + rb + 0) * F + c] = a0;
    support[(size_t)(row0 + rb + 2) * F + c] = a1;
    support[(size_t)(row0 + rb + 4) * F + c] = a2;
    support[(size_t)(row0 + rb + 6) * F + c] = a3;
}

// ---------------- K7: out[i,:] = dinv[i]*(dinv[i]*support[i,:] + sum_e coef*support[col,:]) + bias
__global__ __launch_bounds__(128) void k_spmm(const float* __restrict__ support,
                                              const float* __restrict__ dinv,
                                              const int* __restrict__ offsets,
                                              const int2* __restrict__ csr,
                                              const float* __restrict__ bias,
                                              float* __restrict__ out) {
    int i = blockIdx.x;
    int f = threadIdx.x;
    float di = dinv[i];
    float acc0 = di * support[(size_t)i * F + f];
    float acc1 = 0.f, acc2 = 0.f, acc3 = 0.f;
    int s = offsets[i], e_end = offsets[i + 1];
    int e = s;
    for (; e + 4 <= e_end; e += 4) {
        int2 p0 = csr[e + 0];
        int2 p1 = csr[e + 1];
        int2 p2 = csr[e + 2];
        int2 p3 = csr[e + 3];
        float v0 = support[(size_t)p0.x * F + f];
        float v1 = support[(size_t)p1.x * F + f];
        float v2 = support[(size_t)p2.x * F + f];
        float v3 = support[(size_t)p3.x * F + f];
        acc0 += __int_as_float(p0.y) * v0;
        acc1 += __int_as_float(p1.y) * v1;
        acc2 += __int_as_float(p2.y) * v2;
        acc3 += __int_as_float(p3.y) * v3;
    }
    for (; e < e_end; e++) {
        int2 p = csr[e];
        acc0 += __int_as_float(p.y) * support[(size_t)p.x * F + f];
    }
    float acc = (acc0 + acc1) + (acc2 + acc3);
    out[(size_t)i * F + f] = di * acc + bias[f];
}

extern "C" void kernel_launch(void* const* d_in, const int* in_sizes, int n_in,
                              void* d_out, int out_size, void* d_ws, size_t ws_size,
                              hipStream_t stream) {
    const float* x    = (const float*)d_in[0];
    const int*   adj  = (const int*)d_in[1];   // [2, E] int
    const float* ew   = (const float*)d_in[2];
    const float* w    = (const float*)d_in[3];
    const float* bias = (const float*)d_in[4];
    float* out = (float*)d_out;

    // workspace layout (bytes)
    char* ws = (char*)d_ws;
    float* support  = (float*)(ws + 0);                        // 4 MB
    float* deg      = (float*)(ws + 4 * 1024 * 1024);          // 32 KB
    float* dinv     = (float*)(ws + 4 * 1024 * 1024 + 32768);  // 32 KB
    int*   counts   = (int*)  (ws + 4 * 1024 * 1024 + 65536);  // 32 KB
    int*   offsets  = (int*)  (ws + 4 * 1024 * 1024 + 98304);  // 36 KB (8193 ints)
    int*   cursor   = (int*)  (ws + 4 * 1024 * 1024 + 135168); // 32 KB
    int2*  csr      = (int2*) (ws + 4 * 1024 * 1024 + 167936); // 2 MB

    k_init<<<N_NODES / 256, 256, 0, stream>>>(deg, counts);
    k_deg<<<NE / 256, 256, 0, stream>>>(adj, ew, deg, counts);
    k_dinv<<<N_NODES / 256, 256, 0, stream>>>(deg, dinv);
    k_scan<<<1, 1024, 0, stream>>>(counts, offsets, cursor);
    k_scatter<<<NE / 256, 256, 0, stream>>>(adj, ew, dinv, cursor, csr);
    k_gemm<<<N_NODES / 8, 256, 0, stream>>>(x, w, support);
    k_spmm<<<N_NODES, F, 0, stream>>>(support, dinv, offsets, csr, bias, out);
}